// Round 7
// baseline (169.600 us; speedup 1.0000x reference)
//
#include <hip/hip_runtime.h>

// GATraj fused kernels for MI355X (gfx950) — round 7.
//
// Math simplifications (verified passing rounds 1-6):
//  * LN over the size-1 W_a channel == be_a exactly -> Pos uniform 1/cnt_i.
//  * tmp @ W_g splits; h_i/h_j parts precomputed (A_pre, BH).
//  * r-LayerNorm analytic via 6 moments of centered W_r (KT table).
//
// Round-7 (r6 post-mortem: 12us issue in 42us wall; per-tile chain
// Lst->corr-gather->R-build->LDS-roundtrip->fence->MFMA->BH-gather):
//  * compaction + corr pre-gather moved to prep (Cc[i][idx], padded stride)
//    -> gat reads pairs COALESCED, no nei/atomics/fence in gat
//  * direct A-layout R-build: lane computes its own MFMA A-frag elements
//    from KT[k] (L1-resident) -> no shuffles, no Rt LDS, no fence
//  * next-tile Lst/Cc prefetch; BH gathers issued at tile top
//  * gat LDS = 2KB red only -> bank conflicts ~0

#define NN 768
#define NNP 784  // padded row stride for Lst_g/Cc (cnt+16 tail pad)
#define DD 64
#define EPSF 1e-5f
#define LOG2E 1.44269504f

typedef __attribute__((ext_vector_type(8))) short short8;
typedef __attribute__((ext_vector_type(4))) float float4v;
typedef __attribute__((ext_vector_type(2))) float float2v;
typedef __attribute__((ext_vector_type(4))) unsigned short ushort4v;

__device__ __forceinline__ unsigned short f2bf(float f) {
  unsigned int u = __float_as_uint(f);
  u += 0x7fffu + ((u >> 16) & 1u);  // round-to-nearest-even
  return (unsigned short)(u >> 16);
}

__device__ __forceinline__ float fast_tanh(float x) {
  float e = __builtin_amdgcn_exp2f(fminf(x, 20.f) * (2.f * LOG2E));
  return (e - 1.f) * __builtin_amdgcn_rcpf(e + 1.f);
}

// ---------------------------------------------------------------------------
// Prep kernel, grid = 768 + 1 + 192 blocks x 256 threads:
//   bid < 768  : compact masked-j list of row bid -> Lst_g/cnt_g, pre-gather
//                corr into Cc (coalesced-write), pad 16 tail entries
//   bid == 768 : transposed bf16 Wg_lo pack + W_r moments -> KT/GB/evec
//   bid > 768  : A_pre / {B_pre,hidden} packed GEMVs (wave per row, 4 rows)
// ---------------------------------------------------------------------------
__global__ __launch_bounds__(256) void prep_kernel(
    const float* __restrict__ hidden, const float* __restrict__ Wg,
    const float* __restrict__ bg, const float* __restrict__ Wr,
    const float* __restrict__ br, const float* __restrict__ gr,
    const float* __restrict__ ber, const float* __restrict__ gg,
    const float* __restrict__ beg, const int* __restrict__ nei,
    const float2v* __restrict__ corr2, float* __restrict__ A_pre,
    float2v* __restrict__ BH, float4v* __restrict__ KT,
    float2v* __restrict__ GB, float* __restrict__ evec,
    unsigned short* __restrict__ WgT, int* __restrict__ cnt_g,
    unsigned short* __restrict__ Lst_g, float2v* __restrict__ Cc) {
  const int bid = blockIdx.x;
  const int tid = threadIdx.x;

  if (bid < NN) {
    __shared__ short Lst[NN];
    __shared__ int cLds;
    if (tid == 0) cLds = 0;
    __syncthreads();
#pragma unroll
    for (int rep = 0; rep < 3; ++rep) {
      int jj = tid + rep * 256;
      if (nei[bid * NN + jj] > 0) {
        int idx = atomicAdd(&cLds, 1);
        Lst[idx] = (short)jj;
      }
    }
    __syncthreads();
    const int cnt = cLds;
    if (tid == 0) cnt_g[bid] = cnt;
    for (int idx = tid; idx < cnt; idx += 256) {
      int jp = (int)Lst[idx];
      Lst_g[bid * NNP + idx] = (unsigned short)jp;
      Cc[bid * NNP + idx] = corr2[bid * NN + jp];
    }
    if (cnt > 0 && tid < 16) {  // tail pad so gat needs no index clamps
      int jp0 = (int)Lst[0];
      Lst_g[bid * NNP + cnt + tid] = (unsigned short)jp0;
      Cc[bid * NNP + cnt + tid] = corr2[bid * NN + jp0];
    }
    return;
  }

  if (bid == NN) {
    // Transposed bf16 pack of Wg rows 0..63: WgT[n*64+k] = bf16(Wg[k*64+n])
    for (int idx = tid; idx < DD * DD; idx += 256) {
      int n = idx >> 6, k = idx & 63;
      WgT[idx] = f2bf(Wg[k * DD + n]);
    }
    if (tid < 64) {  // wave 0: W_r moments, KT, GB, evec
      int t = tid;
      float w0 = Wr[t], w1 = Wr[DD + t], bb = br[t];
      float m0 = w0, m1 = w1, mb = bb;
      for (int m = 1; m < 64; m <<= 1) {
        m0 += __shfl_xor(m0, m);
        m1 += __shfl_xor(m1, m);
        mb += __shfl_xor(mb, m);
      }
      m0 *= (1.f / DD);
      m1 *= (1.f / DD);
      mb *= (1.f / DD);
      float a0 = w0 - m0, a1 = w1 - m1, ab = bb - mb;
      float grt = gr[t];
      float4v kt;
      kt[0] = grt * a0;
      kt[1] = grt * a1;
      kt[2] = grt * ab;
      kt[3] = ber[t];
      KT[t] = kt;
      // GB packs the sigmoid-folded LN affine: {-log2e*gg, -log2e*beg}
      float2v gb;
      gb[0] = -LOG2E * gg[t];
      gb[1] = -LOG2E * beg[t];
      GB[t] = gb;
      float e00 = a0 * a0, e11 = a1 * a1, ebb = ab * ab;
      float e01 = a0 * a1, e0b = a0 * ab, e1b = a1 * ab;
      for (int m = 1; m < 64; m <<= 1) {
        e00 += __shfl_xor(e00, m);
        e11 += __shfl_xor(e11, m);
        ebb += __shfl_xor(ebb, m);
        e01 += __shfl_xor(e01, m);
        e0b += __shfl_xor(e0b, m);
        e1b += __shfl_xor(e1b, m);
      }
      if (t == 0) {
        evec[0] = e00 * (1.f / DD);
        evec[1] = e11 * (1.f / DD);
        evec[2] = ebb * (1.f / DD);
        evec[3] = e01 * (1.f / DD);
        evec[4] = e0b * (1.f / DD);
        evec[5] = e1b * (1.f / DD);
      }
    }
    return;
  }

  const int w = tid >> 6;
  const int lane = tid & 63;
  const int i = (bid - NN - 1) * 4 + w;
  float hv = hidden[i * DD + lane];
  float a = bg[lane];
  float b = 0.f;
#pragma unroll 8
  for (int k = 0; k < DD; ++k) {
    float hk = __shfl(hv, k);
    a = fmaf(hk, Wg[(DD + k) * DD + lane], a);
    b = fmaf(hk, Wg[(2 * DD + k) * DD + lane], b);
  }
  A_pre[i * DD + lane] = a;
  float2v bh2;
  bh2[0] = b;
  bh2[1] = hv;
  BH[i * DD + lane] = bh2;
}

// ---------------------------------------------------------------------------
// Monolith: one block per row i (768 x 512 = 8 waves). Waves independently
// process 16-pair tiles (stride 128) from pre-compacted Lst_g/Cc; direct
// A-layout R-build (no LDS roundtrip); in-block close.
// ---------------------------------------------------------------------------
__global__ __launch_bounds__(512, 4) void gat_kernel(
    const float* __restrict__ A_pre, const float2v* __restrict__ BH,
    const float4v* __restrict__ KT, const float2v* __restrict__ GB,
    const float* __restrict__ evec, const unsigned short* __restrict__ WgT,
    const int* __restrict__ cnt_g, const unsigned short* __restrict__ Lst_g,
    const float2v* __restrict__ Cc, const float* __restrict__ hidden,
    const float* __restrict__ cn, const float* __restrict__ bea,
    const float* __restrict__ Ww, const float* __restrict__ bw,
    const float* __restrict__ gw, const float* __restrict__ bew,
    float* __restrict__ out) {
  __shared__ float red[8][DD];

  const int i = blockIdx.x;
  const int tid = threadIdx.x;
  const int wid = tid >> 6;
  const int lane = tid & 63;
  const int quad = lane >> 4;
  const int nl = lane & 15;

  const int cnt = cnt_g[i];

  // Uniform constants (scalar-cached).
  const float e00 = evec[0], e11 = evec[1], ebb = evec[2];
  const float e01 = evec[3], e0b = evec[4], e1b = evec[5];

  // B fragments of Wg_lo (16B contiguous from transposed pack).
  short8 Bf[2][4];
#pragma unroll
  for (int ks = 0; ks < 2; ++ks)
#pragma unroll
    for (int nt = 0; nt < 4; ++nt)
      __builtin_memcpy(&Bf[ks][nt],
                       &WgT[(nt * 16 + nl) * DD + ks * 32 + quad * 8], 16);

  float ngg[4], nbeg[4], pre4[4];
#pragma unroll
  for (int nt = 0; nt < 4; ++nt) {
    int d = nt * 16 + nl;
    float2v gb = GB[d];
    ngg[nt] = gb[0];   // -log2e * gg
    nbeg[nt] = gb[1];  // -log2e * beg
    pre4[nt] = A_pre[i * DD + d];
  }

  float accT[4] = {0.f, 0.f, 0.f, 0.f};

  int base = wid * 16;
  ushort4v l4 = {0, 0, 0, 0};
  float2v cc = {0.f, 0.f};
  if (base < cnt) {
    __builtin_memcpy(&l4, &Lst_g[i * NNP + base + quad * 4], 8);
    cc = Cc[i * NNP + base + nl];
  }

  for (; base < cnt; base += 128) {
    // Prefetch next tile's pair ids + corr (hides L2 latency under this tile).
    const int nb = base + 128;
    ushort4v l4n = {0, 0, 0, 0};
    float2v ccn = {0.f, 0.f};
    if (nb < cnt) {
      __builtin_memcpy(&l4n, &Lst_g[i * NNP + nb + quad * 4], 8);
      ccn = Cc[i * NNP + nb + nl];
    }

    // BH gathers first: addresses known immediately, consumed after MFMA.
    int jpr[4] = {(int)l4[0], (int)l4[1], (int)l4[2], (int)l4[3]};
    float2v bh2[4][4];
#pragma unroll
    for (int rr = 0; rr < 4; ++rr)
#pragma unroll
      for (int nt = 0; nt < 4; ++nt)
        bh2[rr][nt] = BH[jpr[rr] * DD + nt * 16 + nl];

    // Per-pair analytic LN scale (pair = nl, replicated across quads).
    float var = cc[0] * cc[0] * e00 + cc[1] * cc[1] * e11 + ebb +
                2.f * (cc[0] * cc[1] * e01 + cc[0] * e0b + cc[1] * e1b);
    float iv = __builtin_amdgcn_rsqf(var + EPSF);
    float d0 = iv * cc[0], d1 = iv * cc[1];

    // Direct A-layout R-build: lane owns A[m=nl][k=quad*8+e (+32)].
    short8 a0, a1;
#pragma unroll
    for (int e = 0; e < 8; ++e) {
      float4v k0 = KT[quad * 8 + e];
      float4v k1 = KT[32 + quad * 8 + e];
      float r0 = fmaxf(0.f, fmaf(d0, k0[0], fmaf(d1, k0[1], fmaf(iv, k0[2], k0[3]))));
      float r1 = fmaxf(0.f, fmaf(d0, k1[0], fmaf(d1, k1[1], fmaf(iv, k1[2], k1[3]))));
      a0[e] = (short)f2bf(r0);
      a1[e] = (short)f2bf(r1);
    }

    float4v acc[4];
#pragma unroll
    for (int nt = 0; nt < 4; ++nt) {
      float4v z = {0.f, 0.f, 0.f, 0.f};
      z = __builtin_amdgcn_mfma_f32_16x16x32_bf16(a0, Bf[0][nt], z, 0, 0, 0);
      z = __builtin_amdgcn_mfma_f32_16x16x32_bf16(a1, Bf[1][nt], z, 0, 0, 0);
      acc[nt] = z;
    }

    float pv[4];
#pragma unroll
    for (int rr = 0; rr < 4; ++rr)
      pv[rr] = (base + quad * 4 + rr < cnt) ? 1.f : 0.f;

    float y[4][4];
#pragma unroll
    for (int nt = 0; nt < 4; ++nt)
#pragma unroll
      for (int rr = 0; rr < 4; ++rr)
        y[nt][rr] = acc[nt][rr] + pre4[nt] + bh2[rr][nt][0];
#pragma unroll
    for (int rr = 0; rr < 4; ++rr) {
      float s = y[0][rr] + y[1][rr] + y[2][rr] + y[3][rr];
      float qq = y[0][rr] * y[0][rr] + y[1][rr] * y[1][rr] +
                 y[2][rr] * y[2][rr] + y[3][rr] * y[3][rr];
#pragma unroll
      for (int m = 1; m < 16; m <<= 1) {
        s += __shfl_xor(s, m);
        qq += __shfl_xor(qq, m);
      }
      float u = s * (1.f / DD);
      float vv = qq * (1.f / DD) - u * u;
      float inv = __builtin_amdgcn_rsqf(vv + EPSF);
#pragma unroll
      for (int nt = 0; nt < 4; ++nt) {
        float e = __builtin_amdgcn_exp2f(
            fmaf(ngg[nt] * (y[nt][rr] - u), inv, nbeg[nt]));
        float gate = __builtin_amdgcn_rcpf(1.f + e);
        accT[nt] = fmaf(gate * pv[rr], bh2[rr][nt][1], accT[nt]);
      }
    }

    l4 = l4n;
    cc = ccn;
  }

  // Per-wave partials -> LDS (all 8 waves reach here).
#pragma unroll
  for (int nt = 0; nt < 4; ++nt) {
    accT[nt] += __shfl_xor(accT[nt], 16);
    accT[nt] += __shfl_xor(accT[nt], 32);
  }
  if (lane < 16) {
#pragma unroll
    for (int nt = 0; nt < 4; ++nt) red[wid][nt * 16 + nl] = accT[nt];
  }
  __syncthreads();

  if (tid < 64) {  // wave 0 closes the row
    const int d = tid;
    float hs = 0.f;
#pragma unroll
    for (int w = 0; w < 8; ++w) hs += red[w][d];
    float tta = fmaxf(bea[0], 0.f);
    float wgt = (tta > 0.f && cnt > 0) ? __builtin_amdgcn_rcpf((float)cnt)
                                       : (1.f / (float)NN);
    hs *= wgt;  // H_sum[i][d]

    float dotv = bw[d];
#pragma unroll 8
    for (int k = 0; k < DD; ++k) {
      float hk = __shfl(hs, k);
      dotv = fmaf(hk, Ww[k * DD + d], dotv);
    }
    float s = dotv, qq = dotv * dotv;
#pragma unroll
    for (int m = 1; m < 64; m <<= 1) {
      s += __shfl_xor(s, m);
      qq += __shfl_xor(qq, m);
    }
    float u = s * (1.f / DD);
    float var2 = qq * (1.f / DD) - u * u;
    float inv = __builtin_amdgcn_rsqf(var2 + EPSF);
    float val = fmaxf(0.f, fmaf(gw[d], (dotv - u) * inv, bew[d]));
    float Cv = val + cn[i * DD + d];
    out[i * DD + d] = hidden[i * DD + d] + fast_tanh(Cv);
    out[NN * DD + i * DD + d] = Cv;
  }
}

extern "C" void kernel_launch(void* const* d_in, const int* in_sizes, int n_in,
                              void* d_out, int out_size, void* d_ws,
                              size_t ws_size, hipStream_t stream) {
  const float* corr = (const float*)d_in[0];
  const int* nei = (const int*)d_in[1];
  // d_in[2] nei_num: unused by the reference math
  const float* hidden = (const float*)d_in[3];
  const float* cn = (const float*)d_in[4];
  const float* Wr = (const float*)d_in[5];
  const float* br = (const float*)d_in[6];
  const float* gr = (const float*)d_in[7];
  const float* ber = (const float*)d_in[8];
  const float* Wg = (const float*)d_in[9];
  const float* bg = (const float*)d_in[10];
  const float* gg = (const float*)d_in[11];
  const float* beg = (const float*)d_in[12];
  // d_in[13..15] W_a/b_a/g_a: cancel analytically
  const float* bea = (const float*)d_in[16];
  const float* Ww = (const float*)d_in[17];
  const float* bw = (const float*)d_in[18];
  const float* gw = (const float*)d_in[19];
  const float* bew = (const float*)d_in[20];
  float* out = (float*)d_out;

  float* ws = (float*)d_ws;
  float* A_pre = ws;                                     // 49152 floats
  float2v* BH = (float2v*)(ws + 49152);                  // 98304 floats
  float4v* KT = (float4v*)(ws + 147456);                 // 256 floats
  float2v* GB = (float2v*)(ws + 147712);                 // 128 floats
  float* evec = ws + 147840;                             // 16 floats
  unsigned short* WgT = (unsigned short*)(ws + 147856);  // 2048 floats
  int* cnt_g = (int*)(ws + 149904);                      // 768 ints
  unsigned short* Lst_g = (unsigned short*)(ws + 150672);  // 768*784 shorts
  float2v* Cc = (float2v*)(ws + 451728);                 // 768*784 float2

  prep_kernel<<<NN + 1 + NN / 4, 256, 0, stream>>>(
      hidden, Wg, bg, Wr, br, gr, ber, gg, beg, nei, (const float2v*)corr,
      A_pre, BH, KT, GB, evec, WgT, cnt_g, Lst_g, Cc);
  gat_kernel<<<NN, 512, 0, stream>>>(A_pre, BH, KT, GB, evec, WgT, cnt_g,
                                     Lst_g, Cc, hidden, cn, bea, Ww, bw, gw,
                                     bew, out);
}

// Round 9
// 162.263 us; speedup vs baseline: 1.0452x; 1.0452x over previous
//
#include <hip/hip_runtime.h>

// GATraj fused kernels for MI355X (gfx950) — round 9.
//
// Math simplifications (verified passing rounds 1-7):
//  * LN over the size-1 W_a channel == be_a exactly -> Pos uniform 1/cnt_i
//    (or 1/768 if relu(be_a)==0 or cnt==0). W_a/b_a/g_a unused.
//  * tmp @ W_g splits; h_i/h_j parts precomputed (A_pre, BH).
//  * r-LayerNorm analytic via 6 moments of centered W_r (KT table).
//
// Round-9: r8 failed correctness from ONE bug — the compaction loop dropped
// r6's jj < NN guard, so rep 1 (jj = 768..1023) read past row i into row i+1
// and appended ~128 spurious out-of-range pairs. Restored the guard; no other
// changes (clean A/B of the r8 structure: LDS compaction + corr pre-gather,
// bank-padded KT in LDS, direct A-layout R-build, no fences).

#define NN 768
#define DD 64
#define EPSF 1e-5f
#define LOG2E 1.44269504f

typedef __attribute__((ext_vector_type(8))) short short8;
typedef __attribute__((ext_vector_type(4))) float float4v;
typedef __attribute__((ext_vector_type(2))) float float2v;
typedef __attribute__((ext_vector_type(4))) unsigned short ushort4v;

__device__ __forceinline__ unsigned short f2bf(float f) {
  unsigned int u = __float_as_uint(f);
  u += 0x7fffu + ((u >> 16) & 1u);  // round-to-nearest-even
  return (unsigned short)(u >> 16);
}

__device__ __forceinline__ float fast_tanh(float x) {
  float e = __builtin_amdgcn_exp2f(fminf(x, 20.f) * (2.f * LOG2E));
  return (e - 1.f) * __builtin_amdgcn_rcpf(e + 1.f);
}

// ---------------------------------------------------------------------------
// Prep kernel, grid = 193 blocks x 256 threads:
//   bid < 192  : A_pre / {B_pre,hidden} packed GEMVs (wave per row, 4 rows)
//   bid == 192 : transposed bf16 Wg_lo pack + W_r moments -> KT/GB/evec
// ---------------------------------------------------------------------------
__global__ __launch_bounds__(256) void prep_kernel(
    const float* __restrict__ hidden, const float* __restrict__ Wg,
    const float* __restrict__ bg, const float* __restrict__ Wr,
    const float* __restrict__ br, const float* __restrict__ gr,
    const float* __restrict__ ber, const float* __restrict__ gg,
    const float* __restrict__ beg, float* __restrict__ A_pre,
    float2v* __restrict__ BH, float4v* __restrict__ KT,
    float2v* __restrict__ GB, float* __restrict__ evec,
    unsigned short* __restrict__ WgT) {
  const int bid = blockIdx.x;
  const int tid = threadIdx.x;

  if (bid == NN / 4) {
    for (int idx = tid; idx < DD * DD; idx += 256) {
      int n = idx >> 6, k = idx & 63;
      WgT[idx] = f2bf(Wg[k * DD + n]);
    }
    if (tid < 64) {  // wave 0: W_r moments, KT, GB, evec
      int t = tid;
      float w0 = Wr[t], w1 = Wr[DD + t], bb = br[t];
      float m0 = w0, m1 = w1, mb = bb;
      for (int m = 1; m < 64; m <<= 1) {
        m0 += __shfl_xor(m0, m);
        m1 += __shfl_xor(m1, m);
        mb += __shfl_xor(mb, m);
      }
      m0 *= (1.f / DD);
      m1 *= (1.f / DD);
      mb *= (1.f / DD);
      float a0 = w0 - m0, a1 = w1 - m1, ab = bb - mb;
      float grt = gr[t];
      float4v kt;
      kt[0] = grt * a0;
      kt[1] = grt * a1;
      kt[2] = grt * ab;
      kt[3] = ber[t];
      KT[t] = kt;
      // GB packs the sigmoid-folded LN affine: {-log2e*gg, -log2e*beg}
      float2v gb;
      gb[0] = -LOG2E * gg[t];
      gb[1] = -LOG2E * beg[t];
      GB[t] = gb;
      float e00 = a0 * a0, e11 = a1 * a1, ebb = ab * ab;
      float e01 = a0 * a1, e0b = a0 * ab, e1b = a1 * ab;
      for (int m = 1; m < 64; m <<= 1) {
        e00 += __shfl_xor(e00, m);
        e11 += __shfl_xor(e11, m);
        ebb += __shfl_xor(ebb, m);
        e01 += __shfl_xor(e01, m);
        e0b += __shfl_xor(e0b, m);
        e1b += __shfl_xor(e1b, m);
      }
      if (t == 0) {
        evec[0] = e00 * (1.f / DD);
        evec[1] = e11 * (1.f / DD);
        evec[2] = ebb * (1.f / DD);
        evec[3] = e01 * (1.f / DD);
        evec[4] = e0b * (1.f / DD);
        evec[5] = e1b * (1.f / DD);
      }
    }
    return;
  }

  const int w = tid >> 6;
  const int lane = tid & 63;
  const int i = bid * 4 + w;
  float hv = hidden[i * DD + lane];
  float a = bg[lane];
  float b = 0.f;
#pragma unroll 8
  for (int k = 0; k < DD; ++k) {
    float hk = __shfl(hv, k);
    a = fmaf(hk, Wg[(DD + k) * DD + lane], a);
    b = fmaf(hk, Wg[(2 * DD + k) * DD + lane], b);
  }
  A_pre[i * DD + lane] = a;
  float2v bh2;
  bh2[0] = b;
  bh2[1] = hv;
  BH[i * DD + lane] = bh2;
}

// ---------------------------------------------------------------------------
// Monolith: one block per row i (768 x 512 = 8 waves). Compaction writes
// Lst + corr pair data to LDS (+16 pad). Waves process 16-pair tiles
// (stride 128) with direct A-layout R-build; in-block close.
// ---------------------------------------------------------------------------
__global__ __launch_bounds__(512, 4) void gat_kernel(
    const int* __restrict__ nei, const float2v* __restrict__ corr2,
    const float* __restrict__ A_pre, const float2v* __restrict__ BH,
    const float4v* __restrict__ KT, const float2v* __restrict__ GB,
    const float* __restrict__ evec, const unsigned short* __restrict__ WgT,
    const float* __restrict__ hidden, const float* __restrict__ cn,
    const float* __restrict__ bea, const float* __restrict__ Ww,
    const float* __restrict__ bw, const float* __restrict__ gw,
    const float* __restrict__ bew, float* __restrict__ out) {
  __shared__ unsigned short Lst[NN + 16];
  __shared__ float2v CcL[NN + 16];
  __shared__ float4v KTl[72];  // stride-9 padded KT copy
  __shared__ float red[8][DD];
  __shared__ int cLds;

  const int i = blockIdx.x;
  const int tid = threadIdx.x;
  const int wid = tid >> 6;
  const int lane = tid & 63;
  const int quad = lane >> 4;
  const int nl = lane & 15;

  if (tid == 0) cLds = 0;
  if (tid < 64) KTl[tid + (tid >> 3)] = KT[tid];  // pad: k -> k + k/8
  __syncthreads();
  {
    int jj = tid;  // 0..511, always < NN
    if (nei[i * NN + jj] > 0) {
      int idx = atomicAdd(&cLds, 1);
      Lst[idx] = (unsigned short)jj;
      CcL[idx] = corr2[i * NN + jj];
    }
    jj = tid + 512;  // 512..1023: guard against running past row i
    if (jj < NN && nei[i * NN + jj] > 0) {
      int idx = atomicAdd(&cLds, 1);
      Lst[idx] = (unsigned short)jj;
      CcL[idx] = corr2[i * NN + jj];
    }
  }
  __syncthreads();
  const int cnt = cLds;
  if (cnt > 0 && tid < 16) {  // tail pad: no clamps in the tile loop
    Lst[cnt + tid] = Lst[0];
    CcL[cnt + tid] = CcL[0];
  }

  // Uniform constants.
  const float e00 = evec[0], e11 = evec[1], ebb = evec[2];
  const float e01 = evec[3], e0b = evec[4], e1b = evec[5];

  // B fragments of Wg_lo (16B contiguous from transposed pack).
  short8 Bf[2][4];
#pragma unroll
  for (int ks = 0; ks < 2; ++ks)
#pragma unroll
    for (int nt = 0; nt < 4; ++nt)
      __builtin_memcpy(&Bf[ks][nt],
                       &WgT[(nt * 16 + nl) * DD + ks * 32 + quad * 8], 16);

  float ngg[4], nbeg[4], pre4[4];
#pragma unroll
  for (int nt = 0; nt < 4; ++nt) {
    int d = nt * 16 + nl;
    float2v gb = GB[d];
    ngg[nt] = gb[0];   // -log2e * gg
    nbeg[nt] = gb[1];  // -log2e * beg
    pre4[nt] = A_pre[i * DD + d];
  }

  float accT[4] = {0.f, 0.f, 0.f, 0.f};
  __syncthreads();  // pad visible to all waves

  for (int base = wid * 16; base < cnt; base += 128) {
    // Pair ids for this wave's 4 C-rows (one aligned 8B LDS read).
    ushort4v l4;
    __builtin_memcpy(&l4, &Lst[base + quad * 4], 8);
    int jpr[4] = {(int)l4[0], (int)l4[1], (int)l4[2], (int)l4[3]};

    // BH gathers first: consumed only after the MFMAs.
    float2v bh2[4][4];
#pragma unroll
    for (int rr = 0; rr < 4; ++rr)
#pragma unroll
      for (int nt = 0; nt < 4; ++nt)
        bh2[rr][nt] = BH[jpr[rr] * DD + nt * 16 + nl];

    // Per-pair analytic LN scale (pair = nl, replicated across quads).
    float2v cc = CcL[base + nl];
    float var = cc[0] * cc[0] * e00 + cc[1] * cc[1] * e11 + ebb +
                2.f * (cc[0] * cc[1] * e01 + cc[0] * e0b + cc[1] * e1b);
    float iv = __builtin_amdgcn_rsqf(var + EPSF);
    float d0 = iv * cc[0], d1 = iv * cc[1];

    // Direct A-layout R-build: lane owns A[m=nl][k=quad*8+e (+32)].
    short8 a0, a1;
#pragma unroll
    for (int e = 0; e < 8; ++e) {
      int k0i = quad * 9 + e;       // padded idx of k=quad*8+e
      int k1i = 36 + quad * 9 + e;  // padded idx of k=32+quad*8+e
      float4v k0 = KTl[k0i];
      float4v k1 = KTl[k1i];
      float r0 =
          fmaxf(0.f, fmaf(d0, k0[0], fmaf(d1, k0[1], fmaf(iv, k0[2], k0[3]))));
      float r1 =
          fmaxf(0.f, fmaf(d0, k1[0], fmaf(d1, k1[1], fmaf(iv, k1[2], k1[3]))));
      a0[e] = (short)f2bf(r0);
      a1[e] = (short)f2bf(r1);
    }

    float4v acc[4];
#pragma unroll
    for (int nt = 0; nt < 4; ++nt) {
      float4v z = {0.f, 0.f, 0.f, 0.f};
      z = __builtin_amdgcn_mfma_f32_16x16x32_bf16(a0, Bf[0][nt], z, 0, 0, 0);
      z = __builtin_amdgcn_mfma_f32_16x16x32_bf16(a1, Bf[1][nt], z, 0, 0, 0);
      acc[nt] = z;
    }

    float pv[4];
#pragma unroll
    for (int rr = 0; rr < 4; ++rr)
      pv[rr] = (base + quad * 4 + rr < cnt) ? 1.f : 0.f;

    float y[4][4];
#pragma unroll
    for (int nt = 0; nt < 4; ++nt)
#pragma unroll
      for (int rr = 0; rr < 4; ++rr)
        y[nt][rr] = acc[nt][rr] + pre4[nt] + bh2[rr][nt][0];
#pragma unroll
    for (int rr = 0; rr < 4; ++rr) {
      float s = y[0][rr] + y[1][rr] + y[2][rr] + y[3][rr];
      float qq = y[0][rr] * y[0][rr] + y[1][rr] * y[1][rr] +
                 y[2][rr] * y[2][rr] + y[3][rr] * y[3][rr];
#pragma unroll
      for (int m = 1; m < 16; m <<= 1) {
        s += __shfl_xor(s, m);
        qq += __shfl_xor(qq, m);
      }
      float u = s * (1.f / DD);
      float vv = qq * (1.f / DD) - u * u;
      float inv = __builtin_amdgcn_rsqf(vv + EPSF);
#pragma unroll
      for (int nt = 0; nt < 4; ++nt) {
        float e = __builtin_amdgcn_exp2f(
            fmaf(ngg[nt] * (y[nt][rr] - u), inv, nbeg[nt]));
        float gate = __builtin_amdgcn_rcpf(1.f + e);
        accT[nt] = fmaf(gate * pv[rr], bh2[rr][nt][1], accT[nt]);
      }
    }
  }

  // Per-wave partials -> LDS (all 8 waves reach here).
#pragma unroll
  for (int nt = 0; nt < 4; ++nt) {
    accT[nt] += __shfl_xor(accT[nt], 16);
    accT[nt] += __shfl_xor(accT[nt], 32);
  }
  if (lane < 16) {
#pragma unroll
    for (int nt = 0; nt < 4; ++nt) red[wid][nt * 16 + nl] = accT[nt];
  }
  __syncthreads();

  if (tid < 64) {  // wave 0 closes the row
    const int d = tid;
    float hs = 0.f;
#pragma unroll
    for (int w = 0; w < 8; ++w) hs += red[w][d];
    float tta = fmaxf(bea[0], 0.f);
    float wgt = (tta > 0.f && cnt > 0) ? __builtin_amdgcn_rcpf((float)cnt)
                                       : (1.f / (float)NN);
    hs *= wgt;  // H_sum[i][d]

    float dotv = bw[d];
#pragma unroll 8
    for (int k = 0; k < DD; ++k) {
      float hk = __shfl(hs, k);
      dotv = fmaf(hk, Ww[k * DD + d], dotv);
    }
    float s = dotv, qq = dotv * dotv;
#pragma unroll
    for (int m = 1; m < 64; m <<= 1) {
      s += __shfl_xor(s, m);
      qq += __shfl_xor(qq, m);
    }
    float u = s * (1.f / DD);
    float var2 = qq * (1.f / DD) - u * u;
    float inv = __builtin_amdgcn_rsqf(var2 + EPSF);
    float val = fmaxf(0.f, fmaf(gw[d], (dotv - u) * inv, bew[d]));
    float Cv = val + cn[i * DD + d];
    out[i * DD + d] = hidden[i * DD + d] + fast_tanh(Cv);
    out[NN * DD + i * DD + d] = Cv;
  }
}

extern "C" void kernel_launch(void* const* d_in, const int* in_sizes, int n_in,
                              void* d_out, int out_size, void* d_ws,
                              size_t ws_size, hipStream_t stream) {
  const float* corr = (const float*)d_in[0];
  const int* nei = (const int*)d_in[1];
  // d_in[2] nei_num: unused by the reference math
  const float* hidden = (const float*)d_in[3];
  const float* cn = (const float*)d_in[4];
  const float* Wr = (const float*)d_in[5];
  const float* br = (const float*)d_in[6];
  const float* gr = (const float*)d_in[7];
  const float* ber = (const float*)d_in[8];
  const float* Wg = (const float*)d_in[9];
  const float* bg = (const float*)d_in[10];
  const float* gg = (const float*)d_in[11];
  const float* beg = (const float*)d_in[12];
  // d_in[13..15] W_a/b_a/g_a: cancel analytically
  const float* bea = (const float*)d_in[16];
  const float* Ww = (const float*)d_in[17];
  const float* bw = (const float*)d_in[18];
  const float* gw = (const float*)d_in[19];
  const float* bew = (const float*)d_in[20];
  float* out = (float*)d_out;

  float* ws = (float*)d_ws;
  float* A_pre = ws;                                     // 49152 floats
  float2v* BH = (float2v*)(ws + 49152);                  // 98304 floats
  float4v* KT = (float4v*)(ws + 147456);                 // 256 floats
  float2v* GB = (float2v*)(ws + 147712);                 // 128 floats
  float* evec = ws + 147840;                             // 16 floats
  unsigned short* WgT = (unsigned short*)(ws + 147856);  // 4096 shorts

  prep_kernel<<<NN / 4 + 1, 256, 0, stream>>>(hidden, Wg, bg, Wr, br, gr, ber,
                                              gg, beg, A_pre, BH, KT, GB, evec,
                                              WgT);
  gat_kernel<<<NN, 512, 0, stream>>>((const int*)nei, (const float2v*)corr,
                                     A_pre, BH, KT, GB, evec, WgT, hidden, cn,
                                     bea, Ww, bw, gw, bew, out);
}

// Round 10
// 132.565 us; speedup vs baseline: 1.2794x; 1.2240x over previous
//
#include <hip/hip_runtime.h>

// GATraj fused kernels for MI355X (gfx950) — round 10.
//
// Math simplifications (verified passing rounds 1-9):
//  * LN over the size-1 W_a channel == be_a exactly -> Pos uniform 1/cnt_i
//    (or 1/768 if relu(be_a)==0 or cnt==0). W_a/b_a/g_a unused.
//  * tmp @ W_g splits; h_i/h_j parts precomputed (A_pre, BH).
//  * r-LayerNorm analytic via 6 moments of centered W_r (KT table).
//
// Round-10 (r9 post-mortem: direct A-build's 16 hoisted KTl ds_reads -> ~64
// live VGPRs -> scratch spill, FETCH/WRITE 54/62MB, gat 67us): revert to
// r6's proven no-spill R-build (per-lane KT regs + 3 shuffles/pair + Rt LDS
// roundtrip, 42us / FETCH 5.4MB), keep r9's compaction-time corr pre-gather
// (CcL) + tail pad, and de-pressurize the epilogue by loading BH per C-row
// (8 live regs instead of 32).

#define NN 768
#define DD 64
#define EPSF 1e-5f
#define LOG2E 1.44269504f

typedef __attribute__((ext_vector_type(8))) short short8;
typedef __attribute__((ext_vector_type(4))) float float4v;
typedef __attribute__((ext_vector_type(2))) float float2v;
typedef __attribute__((ext_vector_type(4))) unsigned short ushort4v;

__device__ __forceinline__ unsigned short f2bf(float f) {
  unsigned int u = __float_as_uint(f);
  u += 0x7fffu + ((u >> 16) & 1u);  // round-to-nearest-even
  return (unsigned short)(u >> 16);
}

__device__ __forceinline__ float fast_tanh(float x) {
  float e = __builtin_amdgcn_exp2f(fminf(x, 20.f) * (2.f * LOG2E));
  return (e - 1.f) * __builtin_amdgcn_rcpf(e + 1.f);
}

// ---------------------------------------------------------------------------
// Prep kernel, grid = 193 blocks x 256 threads:
//   bid < 192  : A_pre / {B_pre,hidden} packed GEMVs (wave per row, 4 rows)
//   bid == 192 : transposed bf16 Wg_lo pack + W_r moments -> KT/GB/evec
// ---------------------------------------------------------------------------
__global__ __launch_bounds__(256) void prep_kernel(
    const float* __restrict__ hidden, const float* __restrict__ Wg,
    const float* __restrict__ bg, const float* __restrict__ Wr,
    const float* __restrict__ br, const float* __restrict__ gr,
    const float* __restrict__ ber, const float* __restrict__ gg,
    const float* __restrict__ beg, float* __restrict__ A_pre,
    float2v* __restrict__ BH, float4v* __restrict__ KT,
    float2v* __restrict__ GB, float* __restrict__ evec,
    unsigned short* __restrict__ WgT) {
  const int bid = blockIdx.x;
  const int tid = threadIdx.x;

  if (bid == NN / 4) {
    for (int idx = tid; idx < DD * DD; idx += 256) {
      int n = idx >> 6, k = idx & 63;
      WgT[idx] = f2bf(Wg[k * DD + n]);
    }
    if (tid < 64) {  // wave 0: W_r moments, KT, GB, evec
      int t = tid;
      float w0 = Wr[t], w1 = Wr[DD + t], bb = br[t];
      float m0 = w0, m1 = w1, mb = bb;
      for (int m = 1; m < 64; m <<= 1) {
        m0 += __shfl_xor(m0, m);
        m1 += __shfl_xor(m1, m);
        mb += __shfl_xor(mb, m);
      }
      m0 *= (1.f / DD);
      m1 *= (1.f / DD);
      mb *= (1.f / DD);
      float a0 = w0 - m0, a1 = w1 - m1, ab = bb - mb;
      float grt = gr[t];
      float4v kt;
      kt[0] = grt * a0;
      kt[1] = grt * a1;
      kt[2] = grt * ab;
      kt[3] = ber[t];
      KT[t] = kt;
      // GB packs the sigmoid-folded LN affine: {-log2e*gg, -log2e*beg}
      float2v gb;
      gb[0] = -LOG2E * gg[t];
      gb[1] = -LOG2E * beg[t];
      GB[t] = gb;
      float e00 = a0 * a0, e11 = a1 * a1, ebb = ab * ab;
      float e01 = a0 * a1, e0b = a0 * ab, e1b = a1 * ab;
      for (int m = 1; m < 64; m <<= 1) {
        e00 += __shfl_xor(e00, m);
        e11 += __shfl_xor(e11, m);
        ebb += __shfl_xor(ebb, m);
        e01 += __shfl_xor(e01, m);
        e0b += __shfl_xor(e0b, m);
        e1b += __shfl_xor(e1b, m);
      }
      if (t == 0) {
        evec[0] = e00 * (1.f / DD);
        evec[1] = e11 * (1.f / DD);
        evec[2] = ebb * (1.f / DD);
        evec[3] = e01 * (1.f / DD);
        evec[4] = e0b * (1.f / DD);
        evec[5] = e1b * (1.f / DD);
      }
    }
    return;
  }

  const int w = tid >> 6;
  const int lane = tid & 63;
  const int i = bid * 4 + w;
  float hv = hidden[i * DD + lane];
  float a = bg[lane];
  float b = 0.f;
#pragma unroll 8
  for (int k = 0; k < DD; ++k) {
    float hk = __shfl(hv, k);
    a = fmaf(hk, Wg[(DD + k) * DD + lane], a);
    b = fmaf(hk, Wg[(2 * DD + k) * DD + lane], b);
  }
  A_pre[i * DD + lane] = a;
  float2v bh2;
  bh2[0] = b;
  bh2[1] = hv;
  BH[i * DD + lane] = bh2;
}

// ---------------------------------------------------------------------------
// Monolith: one block per row i (768 x 512 = 8 waves). Compaction writes
// Lst + corr pair data to LDS (+16 pad). Waves process 16-pair tiles
// (stride 128) with the r6 shuffle R-build (Rt roundtrip); in-block close.
// ---------------------------------------------------------------------------
__global__ __launch_bounds__(512, 4) void gat_kernel(
    const int* __restrict__ nei, const float2v* __restrict__ corr2,
    const float* __restrict__ A_pre, const float2v* __restrict__ BH,
    const float4v* __restrict__ KT, const float2v* __restrict__ GB,
    const float* __restrict__ evec, const unsigned short* __restrict__ WgT,
    const float* __restrict__ hidden, const float* __restrict__ cn,
    const float* __restrict__ bea, const float* __restrict__ Ww,
    const float* __restrict__ bw, const float* __restrict__ gw,
    const float* __restrict__ bew, float* __restrict__ out) {
  __shared__ unsigned short Lst[NN + 16];
  __shared__ float2v CcL[NN + 16];
  __shared__ __align__(16) unsigned short Rt[8][16 * 72];  // per-wave slice
  __shared__ float red[8][DD];
  __shared__ int cLds;

  const int i = blockIdx.x;
  const int tid = threadIdx.x;
  const int wid = tid >> 6;
  const int lane = tid & 63;
  const int quad = lane >> 4;
  const int nl = lane & 15;

  if (tid == 0) cLds = 0;
  __syncthreads();
  {
    int jj = tid;  // 0..511, always < NN
    if (nei[i * NN + jj] > 0) {
      int idx = atomicAdd(&cLds, 1);
      Lst[idx] = (unsigned short)jj;
      CcL[idx] = corr2[i * NN + jj];
    }
    jj = tid + 512;  // 512..1023: guard against running past row i
    if (jj < NN && nei[i * NN + jj] > 0) {
      int idx = atomicAdd(&cLds, 1);
      Lst[idx] = (unsigned short)jj;
      CcL[idx] = corr2[i * NN + jj];
    }
  }
  __syncthreads();
  const int cnt = cLds;
  if (cnt > 0 && tid < 16) {  // tail pad: no clamps in the tile loop
    Lst[cnt + tid] = Lst[0];
    CcL[cnt + tid] = CcL[0];
  }

  // Uniform constants.
  const float e00 = evec[0], e11 = evec[1], ebb = evec[2];
  const float e01 = evec[3], e0b = evec[4], e1b = evec[5];
  const float4v kt = KT[lane];  // k = lane: {gr*w0h, gr*w1h, gr*bh, ber}

  // B fragments of Wg_lo (16B contiguous from transposed pack).
  short8 Bf[2][4];
#pragma unroll
  for (int ks = 0; ks < 2; ++ks)
#pragma unroll
    for (int nt = 0; nt < 4; ++nt)
      __builtin_memcpy(&Bf[ks][nt],
                       &WgT[(nt * 16 + nl) * DD + ks * 32 + quad * 8], 16);

  float ngg[4], nbeg[4], pre4[4];
#pragma unroll
  for (int nt = 0; nt < 4; ++nt) {
    int d = nt * 16 + nl;
    float2v gb = GB[d];
    ngg[nt] = gb[0];   // -log2e * gg
    nbeg[nt] = gb[1];  // -log2e * beg
    pre4[nt] = A_pre[i * DD + d];
  }

  float accT[4] = {0.f, 0.f, 0.f, 0.f};
  __syncthreads();  // pad visible to all waves

  for (int base = wid * 16; base < cnt; base += 128) {
    // Per-pair analytic LN scale (pair = nl, replicated across quads; LDS
    // same-address broadcast within quads = free).
    float2v cc = CcL[base + nl];
    float var = cc[0] * cc[0] * e00 + cc[1] * cc[1] * e11 + ebb +
                2.f * (cc[0] * cc[1] * e01 + cc[0] * e0b + cc[1] * e1b);
    float iv = __builtin_amdgcn_rsqf(var + EPSF);

    // R build (r6-proven): lane==k writes 16 rows; pair q broadcast via shfl.
#pragma unroll
    for (int q = 0; q < 16; ++q) {
      float sc0 = __shfl(cc[0], q);
      float sc1 = __shfl(cc[1], q);
      float siv = __shfl(iv, q);
      float s3 = fmaf(sc0, kt[0], fmaf(sc1, kt[1], kt[2]));
      float r = fmaxf(0.f, fmaf(siv, s3, kt[3]));
      Rt[wid][q * 72 + lane] = f2bf(r);
    }
    // Same-wave LDS visibility (lgkm drain); no cross-wave barrier needed.
    __builtin_amdgcn_fence(__ATOMIC_ACQ_REL, "workgroup");

    // Pair ids for this wave's 4 C-rows (one aligned 8B LDS read).
    ushort4v l4;
    __builtin_memcpy(&l4, &Lst[base + quad * 4], 8);

    short8 a0, a1;
    __builtin_memcpy(&a0, &Rt[wid][nl * 72 + quad * 8], 16);
    __builtin_memcpy(&a1, &Rt[wid][nl * 72 + 32 + quad * 8], 16);
    float4v acc[4];
#pragma unroll
    for (int nt = 0; nt < 4; ++nt) {
      float4v z = {0.f, 0.f, 0.f, 0.f};
      z = __builtin_amdgcn_mfma_f32_16x16x32_bf16(a0, Bf[0][nt], z, 0, 0, 0);
      z = __builtin_amdgcn_mfma_f32_16x16x32_bf16(a1, Bf[1][nt], z, 0, 0, 0);
      acc[nt] = z;
    }

    // Per-C-row epilogue: only 4 BH float2 live at a time (no spill).
#pragma unroll
    for (int rr = 0; rr < 4; ++rr) {
      const int jpr = (int)l4[rr];
      const float pvr = (base + quad * 4 + rr < cnt) ? 1.f : 0.f;
      float2v b0 = BH[jpr * DD + nl];
      float2v b1 = BH[jpr * DD + 16 + nl];
      float2v b2 = BH[jpr * DD + 32 + nl];
      float2v b3 = BH[jpr * DD + 48 + nl];
      float y0 = acc[0][rr] + pre4[0] + b0[0];
      float y1 = acc[1][rr] + pre4[1] + b1[0];
      float y2 = acc[2][rr] + pre4[2] + b2[0];
      float y3 = acc[3][rr] + pre4[3] + b3[0];
      float s = y0 + y1 + y2 + y3;
      float qq = y0 * y0 + y1 * y1 + y2 * y2 + y3 * y3;
#pragma unroll
      for (int m = 1; m < 16; m <<= 1) {
        s += __shfl_xor(s, m);
        qq += __shfl_xor(qq, m);
      }
      float u = s * (1.f / DD);
      float vv = qq * (1.f / DD) - u * u;
      float inv = __builtin_amdgcn_rsqf(vv + EPSF);
      float g0 = __builtin_amdgcn_exp2f(fmaf(ngg[0] * (y0 - u), inv, nbeg[0]));
      float g1 = __builtin_amdgcn_exp2f(fmaf(ngg[1] * (y1 - u), inv, nbeg[1]));
      float g2 = __builtin_amdgcn_exp2f(fmaf(ngg[2] * (y2 - u), inv, nbeg[2]));
      float g3 = __builtin_amdgcn_exp2f(fmaf(ngg[3] * (y3 - u), inv, nbeg[3]));
      accT[0] = fmaf(__builtin_amdgcn_rcpf(1.f + g0) * pvr, b0[1], accT[0]);
      accT[1] = fmaf(__builtin_amdgcn_rcpf(1.f + g1) * pvr, b1[1], accT[1]);
      accT[2] = fmaf(__builtin_amdgcn_rcpf(1.f + g2) * pvr, b2[1], accT[2]);
      accT[3] = fmaf(__builtin_amdgcn_rcpf(1.f + g3) * pvr, b3[1], accT[3]);
    }
  }

  // Per-wave partials -> LDS (all 8 waves reach here).
#pragma unroll
  for (int nt = 0; nt < 4; ++nt) {
    accT[nt] += __shfl_xor(accT[nt], 16);
    accT[nt] += __shfl_xor(accT[nt], 32);
  }
  if (lane < 16) {
#pragma unroll
    for (int nt = 0; nt < 4; ++nt) red[wid][nt * 16 + nl] = accT[nt];
  }
  __syncthreads();

  if (tid < 64) {  // wave 0 closes the row
    const int d = tid;
    float hs = 0.f;
#pragma unroll
    for (int w = 0; w < 8; ++w) hs += red[w][d];
    float tta = fmaxf(bea[0], 0.f);
    float wgt = (tta > 0.f && cnt > 0) ? __builtin_amdgcn_rcpf((float)cnt)
                                       : (1.f / (float)NN);
    hs *= wgt;  // H_sum[i][d]

    float dotv = bw[d];
#pragma unroll 8
    for (int k = 0; k < DD; ++k) {
      float hk = __shfl(hs, k);
      dotv = fmaf(hk, Ww[k * DD + d], dotv);
    }
    float s = dotv, qq = dotv * dotv;
#pragma unroll
    for (int m = 1; m < 64; m <<= 1) {
      s += __shfl_xor(s, m);
      qq += __shfl_xor(qq, m);
    }
    float u = s * (1.f / DD);
    float var2 = qq * (1.f / DD) - u * u;
    float inv = __builtin_amdgcn_rsqf(var2 + EPSF);
    float val = fmaxf(0.f, fmaf(gw[d], (dotv - u) * inv, bew[d]));
    float Cv = val + cn[i * DD + d];
    out[i * DD + d] = hidden[i * DD + d] + fast_tanh(Cv);
    out[NN * DD + i * DD + d] = Cv;
  }
}

extern "C" void kernel_launch(void* const* d_in, const int* in_sizes, int n_in,
                              void* d_out, int out_size, void* d_ws,
                              size_t ws_size, hipStream_t stream) {
  const float* corr = (const float*)d_in[0];
  const int* nei = (const int*)d_in[1];
  // d_in[2] nei_num: unused by the reference math
  const float* hidden = (const float*)d_in[3];
  const float* cn = (const float*)d_in[4];
  const float* Wr = (const float*)d_in[5];
  const float* br = (const float*)d_in[6];
  const float* gr = (const float*)d_in[7];
  const float* ber = (const float*)d_in[8];
  const float* Wg = (const float*)d_in[9];
  const float* bg = (const float*)d_in[10];
  const float* gg = (const float*)d_in[11];
  const float* beg = (const float*)d_in[12];
  // d_in[13..15] W_a/b_a/g_a: cancel analytically
  const float* bea = (const float*)d_in[16];
  const float* Ww = (const float*)d_in[17];
  const float* bw = (const float*)d_in[18];
  const float* gw = (const float*)d_in[19];
  const float* bew = (const float*)d_in[20];
  float* out = (float*)d_out;

  float* ws = (float*)d_ws;
  float* A_pre = ws;                                     // 49152 floats
  float2v* BH = (float2v*)(ws + 49152);                  // 98304 floats
  float4v* KT = (float4v*)(ws + 147456);                 // 256 floats
  float2v* GB = (float2v*)(ws + 147712);                 // 128 floats
  float* evec = ws + 147840;                             // 16 floats
  unsigned short* WgT = (unsigned short*)(ws + 147856);  // 4096 shorts

  prep_kernel<<<NN / 4 + 1, 256, 0, stream>>>(hidden, Wg, bg, Wr, br, gr, ber,
                                              gg, beg, A_pre, BH, KT, GB, evec,
                                              WgT);
  gat_kernel<<<NN, 512, 0, stream>>>((const int*)nei, (const float2v*)corr,
                                     A_pre, BH, KT, GB, evec, WgT, hidden, cn,
                                     bea, Ww, bw, gw, bew, out);
}

// Round 11
// 129.277 us; speedup vs baseline: 1.3119x; 1.0254x over previous
//
#include <hip/hip_runtime.h>

// GATraj fused kernels for MI355X (gfx950) — round 11.
//
// Math simplifications (verified passing rounds 1-10):
//  * LN over the size-1 W_a channel == be_a exactly -> Pos uniform 1/cnt_i
//    (or 1/768 if relu(be_a)==0 or cnt==0). W_a/b_a/g_a unused.
//  * tmp @ W_g splits; h_i/h_j parts precomputed (A_pre, BH).
//  * r-LayerNorm analytic via 6 moments of centered W_r (KT table).
//
// Round-11 (r10 post-mortem: VGPR_Count=64 proves the compiler sank the 16
// BH gathers to per-rr use sites -> ~4 serialized L2 waits/tile; issue is
// only ~12us of gat's 41us):
//  * l4/cc/all-16 BH loads hoisted to tile top + pinned with an asm memory
//    barrier so they issue ~800+ cycles before first use (under R-build+MFMA)
//  * workgroup fence dropped: same-wave DS ops execute in order and the
//    compiler must assume Rt aliasing, so the roundtrip is already ordered;
//    the fence risked a conservative vmcnt(0) drain defeating the prefetch

#define NN 768
#define DD 64
#define EPSF 1e-5f
#define LOG2E 1.44269504f

typedef __attribute__((ext_vector_type(8))) short short8;
typedef __attribute__((ext_vector_type(4))) float float4v;
typedef __attribute__((ext_vector_type(2))) float float2v;
typedef __attribute__((ext_vector_type(4))) unsigned short ushort4v;

__device__ __forceinline__ unsigned short f2bf(float f) {
  unsigned int u = __float_as_uint(f);
  u += 0x7fffu + ((u >> 16) & 1u);  // round-to-nearest-even
  return (unsigned short)(u >> 16);
}

__device__ __forceinline__ float fast_tanh(float x) {
  float e = __builtin_amdgcn_exp2f(fminf(x, 20.f) * (2.f * LOG2E));
  return (e - 1.f) * __builtin_amdgcn_rcpf(e + 1.f);
}

// ---------------------------------------------------------------------------
// Prep kernel, grid = 193 blocks x 256 threads:
//   bid < 192  : A_pre / {B_pre,hidden} packed GEMVs (wave per row, 4 rows)
//   bid == 192 : transposed bf16 Wg_lo pack + W_r moments -> KT/GB/evec
// ---------------------------------------------------------------------------
__global__ __launch_bounds__(256) void prep_kernel(
    const float* __restrict__ hidden, const float* __restrict__ Wg,
    const float* __restrict__ bg, const float* __restrict__ Wr,
    const float* __restrict__ br, const float* __restrict__ gr,
    const float* __restrict__ ber, const float* __restrict__ gg,
    const float* __restrict__ beg, float* __restrict__ A_pre,
    float2v* __restrict__ BH, float4v* __restrict__ KT,
    float2v* __restrict__ GB, float* __restrict__ evec,
    unsigned short* __restrict__ WgT) {
  const int bid = blockIdx.x;
  const int tid = threadIdx.x;

  if (bid == NN / 4) {
    for (int idx = tid; idx < DD * DD; idx += 256) {
      int n = idx >> 6, k = idx & 63;
      WgT[idx] = f2bf(Wg[k * DD + n]);
    }
    if (tid < 64) {  // wave 0: W_r moments, KT, GB, evec
      int t = tid;
      float w0 = Wr[t], w1 = Wr[DD + t], bb = br[t];
      float m0 = w0, m1 = w1, mb = bb;
      for (int m = 1; m < 64; m <<= 1) {
        m0 += __shfl_xor(m0, m);
        m1 += __shfl_xor(m1, m);
        mb += __shfl_xor(mb, m);
      }
      m0 *= (1.f / DD);
      m1 *= (1.f / DD);
      mb *= (1.f / DD);
      float a0 = w0 - m0, a1 = w1 - m1, ab = bb - mb;
      float grt = gr[t];
      float4v kt;
      kt[0] = grt * a0;
      kt[1] = grt * a1;
      kt[2] = grt * ab;
      kt[3] = ber[t];
      KT[t] = kt;
      // GB packs the sigmoid-folded LN affine: {-log2e*gg, -log2e*beg}
      float2v gb;
      gb[0] = -LOG2E * gg[t];
      gb[1] = -LOG2E * beg[t];
      GB[t] = gb;
      float e00 = a0 * a0, e11 = a1 * a1, ebb = ab * ab;
      float e01 = a0 * a1, e0b = a0 * ab, e1b = a1 * ab;
      for (int m = 1; m < 64; m <<= 1) {
        e00 += __shfl_xor(e00, m);
        e11 += __shfl_xor(e11, m);
        ebb += __shfl_xor(ebb, m);
        e01 += __shfl_xor(e01, m);
        e0b += __shfl_xor(e0b, m);
        e1b += __shfl_xor(e1b, m);
      }
      if (t == 0) {
        evec[0] = e00 * (1.f / DD);
        evec[1] = e11 * (1.f / DD);
        evec[2] = ebb * (1.f / DD);
        evec[3] = e01 * (1.f / DD);
        evec[4] = e0b * (1.f / DD);
        evec[5] = e1b * (1.f / DD);
      }
    }
    return;
  }

  const int w = tid >> 6;
  const int lane = tid & 63;
  const int i = bid * 4 + w;
  float hv = hidden[i * DD + lane];
  float a = bg[lane];
  float b = 0.f;
#pragma unroll 8
  for (int k = 0; k < DD; ++k) {
    float hk = __shfl(hv, k);
    a = fmaf(hk, Wg[(DD + k) * DD + lane], a);
    b = fmaf(hk, Wg[(2 * DD + k) * DD + lane], b);
  }
  A_pre[i * DD + lane] = a;
  float2v bh2;
  bh2[0] = b;
  bh2[1] = hv;
  BH[i * DD + lane] = bh2;
}

// ---------------------------------------------------------------------------
// Monolith: one block per row i (768 x 512 = 8 waves). Compaction writes
// Lst + corr pair data to LDS (+16 pad). Waves process 16-pair tiles
// (stride 128): pinned-early BH gathers, shuffle R-build, MFMA, epilogue.
// ---------------------------------------------------------------------------
__global__ __launch_bounds__(512, 4) void gat_kernel(
    const int* __restrict__ nei, const float2v* __restrict__ corr2,
    const float* __restrict__ A_pre, const float2v* __restrict__ BH,
    const float4v* __restrict__ KT, const float2v* __restrict__ GB,
    const float* __restrict__ evec, const unsigned short* __restrict__ WgT,
    const float* __restrict__ hidden, const float* __restrict__ cn,
    const float* __restrict__ bea, const float* __restrict__ Ww,
    const float* __restrict__ bw, const float* __restrict__ gw,
    const float* __restrict__ bew, float* __restrict__ out) {
  __shared__ unsigned short Lst[NN + 16];
  __shared__ float2v CcL[NN + 16];
  __shared__ __align__(16) unsigned short Rt[8][16 * 72];  // per-wave slice
  __shared__ float red[8][DD];
  __shared__ int cLds;

  const int i = blockIdx.x;
  const int tid = threadIdx.x;
  const int wid = tid >> 6;
  const int lane = tid & 63;
  const int quad = lane >> 4;
  const int nl = lane & 15;

  if (tid == 0) cLds = 0;
  __syncthreads();
  {
    int jj = tid;  // 0..511, always < NN
    if (nei[i * NN + jj] > 0) {
      int idx = atomicAdd(&cLds, 1);
      Lst[idx] = (unsigned short)jj;
      CcL[idx] = corr2[i * NN + jj];
    }
    jj = tid + 512;  // 512..1023: guard against running past row i
    if (jj < NN && nei[i * NN + jj] > 0) {
      int idx = atomicAdd(&cLds, 1);
      Lst[idx] = (unsigned short)jj;
      CcL[idx] = corr2[i * NN + jj];
    }
  }
  __syncthreads();
  const int cnt = cLds;
  if (cnt > 0 && tid < 16) {  // tail pad: no clamps in the tile loop
    Lst[cnt + tid] = Lst[0];
    CcL[cnt + tid] = CcL[0];
  }

  // Uniform constants.
  const float e00 = evec[0], e11 = evec[1], ebb = evec[2];
  const float e01 = evec[3], e0b = evec[4], e1b = evec[5];
  const float4v kt = KT[lane];  // k = lane: {gr*w0h, gr*w1h, gr*bh, ber}

  // B fragments of Wg_lo (16B contiguous from transposed pack).
  short8 Bf[2][4];
#pragma unroll
  for (int ks = 0; ks < 2; ++ks)
#pragma unroll
    for (int nt = 0; nt < 4; ++nt)
      __builtin_memcpy(&Bf[ks][nt],
                       &WgT[(nt * 16 + nl) * DD + ks * 32 + quad * 8], 16);

  float ngg[4], nbeg[4], pre4[4];
#pragma unroll
  for (int nt = 0; nt < 4; ++nt) {
    int d = nt * 16 + nl;
    float2v gb = GB[d];
    ngg[nt] = gb[0];   // -log2e * gg
    nbeg[nt] = gb[1];  // -log2e * beg
    pre4[nt] = A_pre[i * DD + d];
  }

  float accT[4] = {0.f, 0.f, 0.f, 0.f};
  __syncthreads();  // pad visible to all waves

  for (int base = wid * 16; base < cnt; base += 128) {
    // --- Issue phase: pair ids, corr, and ALL 16 BH gathers, pinned early so
    // their latency hides under the R-build + MFMAs below.
    ushort4v l4;
    __builtin_memcpy(&l4, &Lst[base + quad * 4], 8);
    float2v cc = CcL[base + nl];
    float2v bh[4][4];
#pragma unroll
    for (int rr = 0; rr < 4; ++rr) {
      const int jpr = (int)l4[rr];
#pragma unroll
      for (int nt = 0; nt < 4; ++nt) bh[rr][nt] = BH[jpr * DD + nt * 16 + nl];
    }
    asm volatile("" ::: "memory");  // pin: loads above may not sink below

    // Per-pair analytic LN scale (pair = nl, replicated across quads).
    float var = cc[0] * cc[0] * e00 + cc[1] * cc[1] * e11 + ebb +
                2.f * (cc[0] * cc[1] * e01 + cc[0] * e0b + cc[1] * e1b);
    float iv = __builtin_amdgcn_rsqf(var + EPSF);

    // R build: lane==k writes 16 rows; pair q broadcast via shfl. Same-wave
    // DS ops execute in order; compiler orders the reads below via aliasing.
#pragma unroll
    for (int q = 0; q < 16; ++q) {
      float sc0 = __shfl(cc[0], q);
      float sc1 = __shfl(cc[1], q);
      float siv = __shfl(iv, q);
      float s3 = fmaf(sc0, kt[0], fmaf(sc1, kt[1], kt[2]));
      float r = fmaxf(0.f, fmaf(siv, s3, kt[3]));
      Rt[wid][q * 72 + lane] = f2bf(r);
    }

    short8 a0, a1;
    __builtin_memcpy(&a0, &Rt[wid][nl * 72 + quad * 8], 16);
    __builtin_memcpy(&a1, &Rt[wid][nl * 72 + 32 + quad * 8], 16);
    float4v acc[4];
#pragma unroll
    for (int nt = 0; nt < 4; ++nt) {
      float4v z = {0.f, 0.f, 0.f, 0.f};
      z = __builtin_amdgcn_mfma_f32_16x16x32_bf16(a0, Bf[0][nt], z, 0, 0, 0);
      z = __builtin_amdgcn_mfma_f32_16x16x32_bf16(a1, Bf[1][nt], z, 0, 0, 0);
      acc[nt] = z;
    }

    // Epilogue: per-C-row LN + sigmoid gate + accumulate gate*h[j].
#pragma unroll
    for (int rr = 0; rr < 4; ++rr) {
      const float pvr = (base + quad * 4 + rr < cnt) ? 1.f : 0.f;
      float y0 = acc[0][rr] + pre4[0] + bh[rr][0][0];
      float y1 = acc[1][rr] + pre4[1] + bh[rr][1][0];
      float y2 = acc[2][rr] + pre4[2] + bh[rr][2][0];
      float y3 = acc[3][rr] + pre4[3] + bh[rr][3][0];
      float s = y0 + y1 + y2 + y3;
      float qq = y0 * y0 + y1 * y1 + y2 * y2 + y3 * y3;
#pragma unroll
      for (int m = 1; m < 16; m <<= 1) {
        s += __shfl_xor(s, m);
        qq += __shfl_xor(qq, m);
      }
      float u = s * (1.f / DD);
      float vv = qq * (1.f / DD) - u * u;
      float inv = __builtin_amdgcn_rsqf(vv + EPSF);
      float g0 = __builtin_amdgcn_exp2f(fmaf(ngg[0] * (y0 - u), inv, nbeg[0]));
      float g1 = __builtin_amdgcn_exp2f(fmaf(ngg[1] * (y1 - u), inv, nbeg[1]));
      float g2 = __builtin_amdgcn_exp2f(fmaf(ngg[2] * (y2 - u), inv, nbeg[2]));
      float g3 = __builtin_amdgcn_exp2f(fmaf(ngg[3] * (y3 - u), inv, nbeg[3]));
      accT[0] =
          fmaf(__builtin_amdgcn_rcpf(1.f + g0) * pvr, bh[rr][0][1], accT[0]);
      accT[1] =
          fmaf(__builtin_amdgcn_rcpf(1.f + g1) * pvr, bh[rr][1][1], accT[1]);
      accT[2] =
          fmaf(__builtin_amdgcn_rcpf(1.f + g2) * pvr, bh[rr][2][1], accT[2]);
      accT[3] =
          fmaf(__builtin_amdgcn_rcpf(1.f + g3) * pvr, bh[rr][3][1], accT[3]);
    }
  }

  // Per-wave partials -> LDS (all 8 waves reach here).
#pragma unroll
  for (int nt = 0; nt < 4; ++nt) {
    accT[nt] += __shfl_xor(accT[nt], 16);
    accT[nt] += __shfl_xor(accT[nt], 32);
  }
  if (lane < 16) {
#pragma unroll
    for (int nt = 0; nt < 4; ++nt) red[wid][nt * 16 + nl] = accT[nt];
  }
  __syncthreads();

  if (tid < 64) {  // wave 0 closes the row
    const int d = tid;
    float hs = 0.f;
#pragma unroll
    for (int w = 0; w < 8; ++w) hs += red[w][d];
    float tta = fmaxf(bea[0], 0.f);
    float wgt = (tta > 0.f && cnt > 0) ? __builtin_amdgcn_rcpf((float)cnt)
                                       : (1.f / (float)NN);
    hs *= wgt;  // H_sum[i][d]

    float dotv = bw[d];
#pragma unroll 8
    for (int k = 0; k < DD; ++k) {
      float hk = __shfl(hs, k);
      dotv = fmaf(hk, Ww[k * DD + d], dotv);
    }
    float s = dotv, qq = dotv * dotv;
#pragma unroll
    for (int m = 1; m < 64; m <<= 1) {
      s += __shfl_xor(s, m);
      qq += __shfl_xor(qq, m);
    }
    float u = s * (1.f / DD);
    float var2 = qq * (1.f / DD) - u * u;
    float inv = __builtin_amdgcn_rsqf(var2 + EPSF);
    float val = fmaxf(0.f, fmaf(gw[d], (dotv - u) * inv, bew[d]));
    float Cv = val + cn[i * DD + d];
    out[i * DD + d] = hidden[i * DD + d] + fast_tanh(Cv);
    out[NN * DD + i * DD + d] = Cv;
  }
}

extern "C" void kernel_launch(void* const* d_in, const int* in_sizes, int n_in,
                              void* d_out, int out_size, void* d_ws,
                              size_t ws_size, hipStream_t stream) {
  const float* corr = (const float*)d_in[0];
  const int* nei = (const int*)d_in[1];
  // d_in[2] nei_num: unused by the reference math
  const float* hidden = (const float*)d_in[3];
  const float* cn = (const float*)d_in[4];
  const float* Wr = (const float*)d_in[5];
  const float* br = (const float*)d_in[6];
  const float* gr = (const float*)d_in[7];
  const float* ber = (const float*)d_in[8];
  const float* Wg = (const float*)d_in[9];
  const float* bg = (const float*)d_in[10];
  const float* gg = (const float*)d_in[11];
  const float* beg = (const float*)d_in[12];
  // d_in[13..15] W_a/b_a/g_a: cancel analytically
  const float* bea = (const float*)d_in[16];
  const float* Ww = (const float*)d_in[17];
  const float* bw = (const float*)d_in[18];
  const float* gw = (const float*)d_in[19];
  const float* bew = (const float*)d_in[20];
  float* out = (float*)d_out;

  float* ws = (float*)d_ws;
  float* A_pre = ws;                                     // 49152 floats
  float2v* BH = (float2v*)(ws + 49152);                  // 98304 floats
  float4v* KT = (float4v*)(ws + 147456);                 // 256 floats
  float2v* GB = (float2v*)(ws + 147712);                 // 128 floats
  float* evec = ws + 147840;                             // 16 floats
  unsigned short* WgT = (unsigned short*)(ws + 147856);  // 4096 shorts

  prep_kernel<<<NN / 4 + 1, 256, 0, stream>>>(hidden, Wg, bg, Wr, br, gr, ber,
                                              gg, beg, A_pre, BH, KT, GB, evec,
                                              WgT);
  gat_kernel<<<NN, 512, 0, stream>>>((const int*)nei, (const float2v*)corr,
                                     A_pre, BH, KT, GB, evec, WgT, hidden, cn,
                                     bea, Ww, bw, gw, bew, out);
}